// Round 6
// baseline (763.306 us; speedup 1.0000x reference)
//
#include <hip/hip_runtime.h>
#include <math.h>

constexpr int B_ = 4;
constexpr int S_ = 2048;
constexpr int H_ = 16;
constexpr int HID_ = 2048;
constexpr int DK_ = 128;
constexpr int DV_ = 128;

constexpr int CH_ = 16;              // timesteps per LDS chunk
constexpr int NC_ = 8;               // DV split across blocks
constexpr int COLS_ = DV_ / NC_;     // 16 columns per block
constexpr int NCHS_ = S_ / CH_;      // 128 chunks

typedef float f32x4_ __attribute__((ext_vector_type(4)));  // native vec for nt-store

// ---------------- DPP cross-lane helpers (VALU-latency, no DS pipe) --------
template <int CTRL>
__device__ __forceinline__ float dpp_add(float x) {
  int y = __builtin_amdgcn_update_dpp(0, __float_as_int(x), CTRL, 0xF, 0xF, true);
  return x + __int_as_float(y);
}
// butterfly sum over aligned 16-lane groups; every lane gets the total
__device__ __forceinline__ float sum16(float x) {
  x = dpp_add<0xB1>(x);   // quad_perm [1,0,3,2]  (xor 1)
  x = dpp_add<0x4E>(x);   // quad_perm [2,3,0,1]  (xor 2)
  x = dpp_add<0x141>(x);  // row_half_mirror      (xor 7)
  x = dpp_add<0x140>(x);  // row_mirror           (xor 15)
  return x;
}
__device__ __forceinline__ float swz_xor16(float x) {
  // BitMode swizzle: lane ^= 16 within each 32-lane group
  int y = __builtin_amdgcn_ds_swizzle(__float_as_int(x), 0x401F);
  return __int_as_float(y);
}

// ---------------------------------------------------------------------------
// Gates: decay/beta for all (b,s,h). Verified in round 1.
// ---------------------------------------------------------------------------
__global__ __launch_bounds__(256) void gates_kernel(
    const float* __restrict__ x, const float* __restrict__ Wa,
    const float* __restrict__ Wb, const float* __restrict__ dt_bias,
    const float* __restrict__ A_log, float* __restrict__ decay,
    float* __restrict__ beta) {
  const int r0 = blockIdx.x * 4;
  const int w = threadIdx.x >> 6;
  const int lane = threadIdx.x & 63;

  const float4* x4 = reinterpret_cast<const float4*>(x);
  const float4* wbase = reinterpret_cast<const float4*>(w < 2 ? Wa : Wb);
  const int h0 = (w & 1) * 8;

  float acc[4][8];
#pragma unroll
  for (int i = 0; i < 4; ++i)
#pragma unroll
    for (int j = 0; j < 8; ++j) acc[i][j] = 0.f;

  for (int m = 0; m < 8; ++m) {
    const int kk = m * 64 + lane;
    float4 xv[4], wv[8];
#pragma unroll
    for (int i = 0; i < 4; ++i) xv[i] = x4[(size_t)(r0 + i) * (HID_ / 4) + kk];
#pragma unroll
    for (int j = 0; j < 8; ++j) wv[j] = wbase[(size_t)(h0 + j) * (HID_ / 4) + kk];
#pragma unroll
    for (int i = 0; i < 4; ++i)
#pragma unroll
      for (int j = 0; j < 8; ++j) {
        acc[i][j] = fmaf(xv[i].x, wv[j].x, acc[i][j]);
        acc[i][j] = fmaf(xv[i].y, wv[j].y, acc[i][j]);
        acc[i][j] = fmaf(xv[i].z, wv[j].z, acc[i][j]);
        acc[i][j] = fmaf(xv[i].w, wv[j].w, acc[i][j]);
      }
  }

  float myval = 0.f;
#pragma unroll
  for (int i = 0; i < 4; ++i)
#pragma unroll
    for (int j = 0; j < 8; ++j) {
      float v = sum16(acc[i][j]);
      v += __shfl_xor(v, 16, 64);
      v += __shfl_xor(v, 32, 64);
      if (lane == i * 8 + j) myval = v;
    }
  if (lane < 32) {
    const int i = lane >> 3, j = lane & 7;
    const int h = h0 + j;
    const int row = r0 + i;
    if (w < 2) {
      const float za = myval + dt_bias[h];
      const float sp = (za > 20.f) ? za : log1pf(expf(za));
      decay[(size_t)row * H_ + h] = expf(-expf(A_log[h]) * sp);
    } else {
      beta[(size_t)row * H_ + h] = myval;
    }
  }
}

// ---------------------------------------------------------------------------
// Serial scan, 4-rows-per-lane variant for 2x occupancy:
//  - lane (sub=tid&31, col=tid>>5) owns rows 4sub..4sub+3 of column col;
//    16 cols/block (NC_=8), 512 thr/block, grid 512 -> 2 blocks/CU,
//    16 waves/CU = 4 waves/SIMD (was 2) to fill issue during chain stalls.
//  - reduce = sum16 (DPP) + xor16 (ds_swizzle): total over 32 subs.
//  - frag slots linear: float4 slot sub = rows 4sub..4sub+3 (no swizzle).
//  - 16-step loop fully unrolled, double-buffered frag regs, base+imm LDS.
//  - outputs staged in lo[], stored as float4 (two half-line writers of one
//    128B line are on the same XCD -> merge in L2, no RMW amp).
//  - XCD swizzle: all 8 c-blocks of one (b,h) on one XCD (k/q L2 sharing).
// out_t = g*(q.s_prev) + (q.k)*delta, qk precomputed at staging.
// ---------------------------------------------------------------------------
__global__ __launch_bounds__(512) void scan_kernel(
    const float* __restrict__ qg, const float* __restrict__ kg,
    const float* __restrict__ vg, const float* __restrict__ decay,
    const float* __restrict__ betag, float* __restrict__ outg) {
  // id = (g&7) + 8*c + 64*(g>>3): id%8 == g&7 -> same XCD for all c of (b,h)
  const int id = blockIdx.x;
  const int g_ = (id & 7) | ((id >> 6) << 3);
  const int c = (id >> 3) & 7;
  const int h = g_ & 15;
  const int b = g_ >> 4;
  const int tid = threadIdx.x;
  const int sub = tid & 31;
  const int col = tid >> 5;  // 0..15

  __shared__ __align__(16) float lk[CH_ * DK_];
  __shared__ __align__(16) float lq[CH_ * DK_];
  __shared__ __align__(16) float lv[CH_ * COLS_];
  __shared__ __align__(16) float lgbq[CH_ * 4];   // (g, beta, qk, pad)
  __shared__ __align__(16) float lo[CH_ * COLS_];

  const float4* k4 = reinterpret_cast<const float4*>(kg);
  const float4* q4 = reinterpret_cast<const float4*>(qg);
  const float4* v4 = reinterpret_cast<const float4*>(vg);
  float4* lk4 = reinterpret_cast<float4*>(lk);
  float4* lq4 = reinterpret_cast<float4*>(lq);
  float4* lv4 = reinterpret_cast<float4*>(lv);
  const f32x4_* lo4n = reinterpret_cast<const f32x4_*>(lo);

  // staging: thread stages one k/q float4 at (u0, d4), linear slot
  const int u0 = tid >> 5, d4 = tid & 31;

  float4 pk = {}, pq = {}, pv = {};
  float pg = 0.f, pb = 0.f;

  auto loadRegs = [&](int s0) {
    const size_t base = ((size_t)(b * S_ + s0 + u0) * H_ + h) * (DK_ / 4) + d4;
    pk = k4[base];
    pq = q4[base];
    if (tid < 64) {
      const int uu = tid >> 2, e = tid & 3;
      pv = v4[((size_t)(b * S_ + s0 + uu) * H_ + h) * (DV_ / 4) + c * (COLS_ / 4) + e];
    }
    if (tid >= 128 && tid < 128 + CH_)
      pg = decay[(size_t)(b * S_ + s0 + (tid - 128)) * H_ + h];
    if (tid >= 160 && tid < 160 + CH_)
      pb = betag[(size_t)(b * S_ + s0 + (tid - 160)) * H_ + h];
  };

  auto writeLDS = [&]() {
    lk4[u0 * 32 + d4] = pk;
    lq4[u0 * 32 + d4] = pq;
    if (tid < 64) {
      const int uu = tid >> 2, e = tid & 3;
      lv4[uu * (COLS_ / 4) + e] = pv;
    }
    if (tid >= 128 && tid < 128 + CH_) lgbq[(tid - 128) * 4 + 0] = pg;
    if (tid >= 160 && tid < 160 + CH_) lgbq[(tid - 160) * 4 + 1] = pb;
    // qk[u] = q_u . k_u : per-lane dot4 partials reduced over the 32 lanes of u
    float p = fmaf(pq.x, pk.x, fmaf(pq.y, pk.y, fmaf(pq.z, pk.z, pq.w * pk.w)));
    p = sum16(p);
    p += swz_xor16(p);
    if ((tid & 31) == 0) lgbq[u0 * 4 + 2] = p;
  };

  float st[4];  // rows sub*4+r of column col
#pragma unroll
  for (int r = 0; r < 4; ++r) st[r] = 0.f;

  // double-buffered fragment registers (indices literal after unroll)
  float4 kA[2], qA[2], gq[2];
  float fv[2];

  loadRegs(0);
  writeLDS();
  __syncthreads();

  for (int ci = 0; ci < NCHS_; ++ci) {
    const int s0 = ci * CH_;
    if (ci + 1 < NCHS_) loadRegs(s0 + CH_);  // global prefetch for next chunk

    // prime buffer 0
    kA[0] = lk4[0 * 32 + sub];
    qA[0] = lq4[0 * 32 + sub];
    fv[0] = lv[0 * COLS_ + col];
    gq[0] = *reinterpret_cast<const float4*>(&lgbq[0]);

#pragma unroll
    for (int u = 0; u < CH_; ++u) {
      const int p = u & 1;
      if (u + 1 < CH_) {
        const int n = p ^ 1;
        kA[n] = lk4[(u + 1) * 32 + sub];
        qA[n] = lq4[(u + 1) * 32 + sub];
        fv[n] = lv[(u + 1) * COLS_ + col];
        gq[n] = *reinterpret_cast<const float4*>(&lgbq[(u + 1) * 4]);
      }
      const float gg = gq[p].x, bt = gq[p].y, qk = gq[p].z;
      float vp = kA[p].x * st[0];
      float op = qA[p].x * st[0];
      vp = fmaf(kA[p].y, st[1], vp); op = fmaf(qA[p].y, st[1], op);
      vp = fmaf(kA[p].z, st[2], vp); op = fmaf(qA[p].z, st[2], op);
      vp = fmaf(kA[p].w, st[3], vp); op = fmaf(qA[p].w, st[3], op);
      vp = sum16(vp);
      vp += swz_xor16(vp);
      op = sum16(op);
      op += swz_xor16(op);
      const float dlt = (fv[p] - gg * vp) * bt;
      st[0] = fmaf(kA[p].x, dlt, st[0] * gg);
      st[1] = fmaf(kA[p].y, dlt, st[1] * gg);
      st[2] = fmaf(kA[p].z, dlt, st[2] * gg);
      st[3] = fmaf(kA[p].w, dlt, st[3] * gg);
      if (sub == 0) lo[u * COLS_ + col] = fmaf(qk, dlt, gg * op);
    }

    __syncthreads();  // steps done: lo complete, lk/lq/lv/lgbq reads done

    // coalesced out store (nontemporal, native vec type)
    if (tid < 64) {
      const int t = tid >> 2, e = tid & 3;
      __builtin_nontemporal_store(
          lo4n[t * (COLS_ / 4) + e],
          reinterpret_cast<f32x4_*>(
              &outg[((size_t)(b * S_ + s0 + t) * H_ + h) * DV_ + c * COLS_ + e * 4]));
    }
    if (ci + 1 < NCHS_) writeLDS();

    __syncthreads();  // next chunk's LDS visible
  }
}

extern "C" void kernel_launch(void* const* d_in, const int* in_sizes, int n_in,
                              void* d_out, int out_size, void* d_ws, size_t ws_size,
                              hipStream_t stream) {
  const float* x = (const float*)d_in[0];
  const float* q = (const float*)d_in[1];
  const float* k = (const float*)d_in[2];
  const float* v = (const float*)d_in[3];
  const float* Wa = (const float*)d_in[4];
  const float* Wb = (const float*)d_in[5];
  const float* dtb = (const float*)d_in[6];
  const float* Alog = (const float*)d_in[7];
  float* out = (float*)d_out;

  float* decay = (float*)d_ws;
  float* beta = decay + (size_t)B_ * S_ * H_;

  gates_kernel<<<B_ * S_ / 4, 256, 0, stream>>>(x, Wa, Wb, dtb, Alog, decay, beta);
  scan_kernel<<<NC_ * H_ * B_, 512, 0, stream>>>(q, k, v, decay, beta, out);
}